// Round 3
// baseline (13329.639 us; speedup 1.0000x reference)
//
#include <hip/hip_runtime.h>
#include <cstdint>

typedef __attribute__((ext_vector_type(8))) short bf16x8;
typedef __attribute__((ext_vector_type(4))) float f32x4;

#define AS1 __attribute__((address_space(1)))
#define AS3 __attribute__((address_space(3)))

__device__ __forceinline__ unsigned short f2bf(float f) {
  unsigned int u = __builtin_bit_cast(unsigned int, f);
  return (unsigned short)((u + 0x7fffu + ((u >> 16) & 1u)) >> 16);
}
__device__ __forceinline__ float bf2f(unsigned short h) {
  unsigned int u = ((unsigned int)h) << 16;
  return __builtin_bit_cast(float, u);
}
__device__ __forceinline__ float sigm(float x) { return 1.f / (1.f + __expf(-x)); }
__device__ __forceinline__ float tanh_f(float x) {
  float e = __expf(2.f * x);          // inf-safe: e=inf -> 1, e=0 -> -1
  return 1.f - 2.f / (e + 1.f);
}
__device__ __forceinline__ void gload16(const void* g, void* l) {
  __builtin_amdgcn_global_load_lds((const AS1 unsigned int*)g, (AS3 unsigned int*)l, 16, 0, 0);
}
// XOR-swizzle within a [rows][64]-bf16 tile (T2; pre-swizzled global source +
// swizzled ds_read, linear LDS dest — rule #21).
__device__ __forceinline__ int swz(int e) { return e ^ (((e >> 6) & 7) << 3); }

// ---------------- setup / conversion kernels ----------------

__global__ __launch_bounds__(256) void conv_wh_kernel(
    const float4* __restrict__ w0, const float4* __restrict__ w1,
    const float4* __restrict__ w2, const float4* __restrict__ w3,
    unsigned long long* __restrict__ dst) {
  int i = blockIdx.x * 256 + threadIdx.x;           // 0 .. 1M-1 (float4 units)
  int g = i >> 18;                                  // 262144 float4 per matrix
  const float4* s = g == 0 ? w0 : g == 1 ? w1 : g == 2 ? w2 : w3;
  float4 v = s[i & 0x3FFFF];
  unsigned long long p = (unsigned long long)f2bf(v.x) |
                         ((unsigned long long)f2bf(v.y) << 16) |
                         ((unsigned long long)f2bf(v.z) << 32) |
                         ((unsigned long long)f2bf(v.w) << 48);
  dst[i] = p;
}

__global__ __launch_bounds__(256) void conv_wiT_kernel(
    const float* __restrict__ w0, const float* __restrict__ w1,
    const float* __restrict__ w2, const float* __restrict__ w3,
    unsigned short* __restrict__ dst) {
  __shared__ unsigned short ls[64][72];
  int bid = blockIdx.x;                 // 0..1023 : 4 gates x 16x16 tiles
  int g = bid >> 8;
  int t2 = bid & 255;
  int tj = t2 & 15, tk = t2 >> 4;
  const float* W = g == 0 ? w0 : g == 1 ? w1 : g == 2 ? w2 : w3;
  int k0 = tk * 64, j0 = tj * 64;
  int ty = threadIdx.x >> 6, tx = threadIdx.x & 63;
#pragma unroll
  for (int r = 0; r < 16; ++r) {
    int k = k0 + ty * 16 + r;
    ls[tx][ty * 16 + r] = f2bf(W[k * 1024 + j0 + tx]);  // ls[j_local][k_local]
  }
  __syncthreads();
#pragma unroll
  for (int r = 0; r < 16; ++r) {
    int jl = ty * 16 + r;
    dst[(size_t)(g * 1024 + j0 + jl) * 1024 + k0 + tx] = ls[jl][tx];
  }
}

__global__ __launch_bounds__(256) void conv_bias_kernel(
    const float* __restrict__ b0, const float* __restrict__ b1,
    const float* __restrict__ b2, const float* __restrict__ b3,
    float* __restrict__ dst) {
  int i = blockIdx.x * 256 + threadIdx.x;  // 0..4095
  const float* s = (i >> 10) == 0 ? b0 : (i >> 10) == 1 ? b1 : (i >> 10) == 2 ? b2 : b3;
  dst[i] = s[i & 1023];
}

__global__ __launch_bounds__(256) void conv_x_kernel(
    const float4* __restrict__ src, unsigned long long* __restrict__ dst, int n4) {
  int i = blockIdx.x * 256 + threadIdx.x;
  if (i < n4) {
    float4 v = src[i];
    dst[i] = (unsigned long long)f2bf(v.x) |
             ((unsigned long long)f2bf(v.y) << 16) |
             ((unsigned long long)f2bf(v.z) << 32) |
             ((unsigned long long)f2bf(v.w) << 48);
  }
}

// ---------------- input-projection GEMM ----------------
// m97 structure, 128x128 tile, BK=64, 4 waves (2x2). LB(256,3) targets
// 3 waves/SIMD (arch+acc <= 170 regs). Epilogue bounces C through LDS so
// global stores are full 16B lines (kills write-allocate over-fetch).
__global__ __launch_bounds__(256, 3) void xproj_gemm_kernel(
    const unsigned short* __restrict__ A,   // [Mc][1024]
    const unsigned short* __restrict__ Bt,  // [4096][1024]
    unsigned short* __restrict__ C,         // [Mc][4096]
    int Mc) {
  __shared__ __align__(16) char smem[34816];          // 34 KB union
  unsigned short* lsA = (unsigned short*)smem;        // [128*64]
  unsigned short* lsB = lsA + 8192;                   // [128*64]
  int bx = blockIdx.x;
  int bm = bx >> 5, bn = bx & 31;
  int m0 = bm * 128, n0 = bn * 128;
  int tid = threadIdx.x, w = tid >> 6, lane = tid & 63;
  int wm = w >> 1, wn = w & 1;
  int l15 = lane & 15, l4 = lane >> 4;

  f32x4 acc[4][4];
#pragma unroll
  for (int i = 0; i < 4; ++i)
#pragma unroll
    for (int j = 0; j < 4; ++j) acc[i][j] = (f32x4)0.f;

  for (int ks = 0; ks < 16; ++ks) {
    int kk = ks * 64;
    __syncthreads();   // everyone done reading previous tile
#pragma unroll
    for (int ld = 0; ld < 4; ++ld) {
      int cid = ld * 256 + tid;
      int r = cid >> 3, kc = (cid & 7) * 8;
      int sk = kk + (kc ^ ((r & 7) << 3));
      gload16(&A[(size_t)(m0 + r) * 1024 + sk], &lsA[(ld * 256 + w * 64) * 8]);
      gload16(&Bt[(size_t)(n0 + r) * 1024 + sk], &lsB[(ld * 256 + w * 64) * 8]);
    }
    __syncthreads();   // data ready (drains vmcnt)
    bf16x8 af[4][2], bfr[4][2];
#pragma unroll
    for (int cm = 0; cm < 4; ++cm)
#pragma unroll
      for (int kss = 0; kss < 2; ++kss) {
        int e = (wm * 64 + cm * 16 + l15) * 64 + kss * 32 + l4 * 8;
        af[cm][kss] = *(const bf16x8*)&lsA[swz(e)];
      }
#pragma unroll
    for (int cn = 0; cn < 4; ++cn)
#pragma unroll
      for (int kss = 0; kss < 2; ++kss) {
        int e = (wn * 64 + cn * 16 + l15) * 64 + kss * 32 + l4 * 8;
        bfr[cn][kss] = *(const bf16x8*)&lsB[swz(e)];
      }
#pragma unroll
    for (int cm = 0; cm < 4; ++cm)
#pragma unroll
      for (int cn = 0; cn < 4; ++cn)
#pragma unroll
        for (int kss = 0; kss < 2; ++kss)
          acc[cm][cn] = __builtin_amdgcn_mfma_f32_16x16x32_bf16(
              af[cm][kss], bfr[cn][kss], acc[cm][cn], 0, 0, 0);
  }

  // ---- epilogue: acc -> LDS (bf16) -> coalesced 16B global stores ----
  __syncthreads();
  unsigned short* lsC = (unsigned short*)smem;   // [128][136]
#pragma unroll
  for (int cm = 0; cm < 4; ++cm)
#pragma unroll
    for (int cn = 0; cn < 4; ++cn)
#pragma unroll
      for (int r = 0; r < 4; ++r) {
        int row = wm * 64 + cm * 16 + l4 * 4 + r;
        int col = wn * 64 + cn * 16 + l15;
        lsC[row * 136 + col] = f2bf(acc[cm][cn][r]);
      }
  __syncthreads();
#pragma unroll
  for (int u = 0; u < 8; ++u) {
    int chunk = u * 256 + tid;        // 0..2047 : 128 rows x 16 chunks of 16B
    int row = chunk >> 4, c8 = chunk & 15;
    bf16x8 v = *(const bf16x8*)&lsC[row * 136 + c8 * 8];
    *(bf16x8*)&C[(size_t)(m0 + row) * 4096 + n0 + c8 * 8] = v;
  }
}

// ---------------- persistent wavefront LSTM ----------------
// One launch per chunk of steps. 256 blocks (1/CU nominal; 80KB LDS => 2/CU
// capacity so co-residency has slack). Block (bb,bj) owns the (64 batch x
// 64 hidden) tile for all 4 gates. j-columns evolve independently: step t+1
// block (bb,bj) depends only on the 16 blocks (*,bj) of step t -> per-(t,bj)
// counters with device-scope atomics + agent release/acquire fences (G16).
__global__ __launch_bounds__(512) void lstm_persist_kernel(
    const unsigned short* __restrict__ Wh,   // [4096][1024]
    unsigned short* __restrict__ hT0,        // ping-pong hT buffers
    unsigned short* __restrict__ hT1,
    const unsigned short* __restrict__ Xp,   // [tc][1024][4096]
    const float* __restrict__ bias,          // [4096]
    float* __restrict__ cst,                 // [1024*1024] fp32 cell state
    float* __restrict__ out,                 // d_out base
    unsigned int* __restrict__ cnt,          // [128][16] step completion
    int t0, int tc) {
  __shared__ unsigned short lsA[2][256 * 64];  // 4 gates x 64 rows x BK
  __shared__ unsigned short lsB[2][64 * 64];
  int bx = blockIdx.x;
  int xcd = bx & 7, idx = bx >> 3;             // block->XCD round-robin %8
  int bb = xcd * 2 + (idx & 1);                // XCD-local Wh slice (1MB/XCD)
  int bj = idx >> 1;
  int b0 = bb * 64, j0 = bj * 64;
  int tid = threadIdx.x, w = tid >> 6, lane = tid & 63;
  int wm = w >> 1, wn = w & 1;
  int l15 = lane & 15, l4 = lane >> 4;

  for (int i = 0; i < tc; ++i) {
    int t = t0 + i;
    const unsigned short* hT = (t & 1) ? hT1 : hT0;
    unsigned short* hT_next = (t & 1) ? hT0 : hT1;
    const unsigned short* Xpt = Xp + (size_t)i * 4194304;
    float* out_h = out + (size_t)t * 1048576;

    // ---- gate: wait for all 16 producers of hT rows [j0,j0+64) ----
    if (t > 0) {
      if (tid == 0) {
        unsigned int v; int guard = 0;
        while ((v = __hip_atomic_load(&cnt[(t - 1) * 16 + bj],
                                      __ATOMIC_RELAXED,
                                      __HIP_MEMORY_SCOPE_AGENT)) < 16u) {
          if (++guard > (1 << 24)) break;      // bounded: fail loud, not hang
          __builtin_amdgcn_s_sleep(2);
        }
      }
      __syncthreads();
      __builtin_amdgcn_fence(__ATOMIC_ACQUIRE, "agent");  // inv L1/L2
    }

    f32x4 acc[4][2];
#pragma unroll
    for (int g = 0; g < 4; ++g)
#pragma unroll
      for (int n = 0; n < 2; ++n) acc[g][n] = (f32x4)0.f;

    auto stage = [&](int buf, int kk) {        // 5 gload16 per thread
#pragma unroll
      for (int ld = 0; ld < 4; ++ld) {
        int cid = ld * 512 + tid;
        int r = cid >> 3, kc = (cid & 7) * 8;  // r: 0..255 local row
        int sk = kk + (kc ^ ((r & 7) << 3));
        int grow = (r >> 6) * 1024 + b0 + (r & 63);
        gload16(&Wh[(size_t)grow * 1024 + sk], &lsA[buf][(ld * 512 + w * 64) * 8]);
      }
      {
        int r = tid >> 3, kc = (tid & 7) * 8;  // r: 0..63
        int sk = kk + (kc ^ ((r & 7) << 3));
        gload16(&hT[(size_t)(j0 + r) * 1024 + sk], &lsB[buf][w * 512]);
      }
    };
    auto compute = [&](int buf) {
      bf16x8 af[4][2], bfr[2][2];
#pragma unroll
      for (int g = 0; g < 4; ++g)
#pragma unroll
        for (int kss = 0; kss < 2; ++kss) {
          int e = (g * 64 + wm * 16 + l15) * 64 + kss * 32 + l4 * 8;
          af[g][kss] = *(const bf16x8*)&lsA[buf][swz(e)];
        }
#pragma unroll
      for (int n = 0; n < 2; ++n)
#pragma unroll
        for (int kss = 0; kss < 2; ++kss) {
          int e = (wn * 32 + n * 16 + l15) * 64 + kss * 32 + l4 * 8;
          bfr[n][kss] = *(const bf16x8*)&lsB[buf][swz(e)];
        }
#pragma unroll
      for (int g = 0; g < 4; ++g)
#pragma unroll
        for (int n = 0; n < 2; ++n)
#pragma unroll
          for (int kss = 0; kss < 2; ++kss)
            acc[g][n] = __builtin_amdgcn_mfma_f32_16x16x32_bf16(
                af[g][kss], bfr[n][kss], acc[g][n], 0, 0, 0);
    };

    // ---- 16-iter K-loop, dbuf, 1-deep prefetch, counted vmcnt ----
    stage(0, 0);
#pragma unroll
    for (int it = 0; it < 16; ++it) {
      if (it + 1 < 16) {
        stage((it + 1) & 1, (it + 1) * 64);
        asm volatile("s_waitcnt vmcnt(5)" ::: "memory");  // stage(it) landed
      } else {
        asm volatile("s_waitcnt vmcnt(0)" ::: "memory");
      }
      __builtin_amdgcn_sched_barrier(0);
      __builtin_amdgcn_s_barrier();
      __builtin_amdgcn_sched_barrier(0);
      compute(it & 1);
      asm volatile("s_waitcnt lgkmcnt(0)" ::: "memory");  // my ds_reads done
      __builtin_amdgcn_sched_barrier(0);
      __builtin_amdgcn_s_barrier();
      __builtin_amdgcn_sched_barrier(0);
    }

    // ---- epilogue: gates + cell/hidden update ----
#pragma unroll
    for (int n = 0; n < 2; ++n) {
      int j = j0 + wn * 32 + n * 16 + l15;
      float bi_ = bias[j];
      float bf_ = bias[1024 + j];
      float bg_ = bias[2048 + j];
      float bo_ = bias[3072 + j];
      int bbase = b0 + wm * 16 + l4 * 4;
      float hn[4], cn[4];
#pragma unroll
      for (int r = 0; r < 4; ++r) {
        int b = bbase + r;
        size_t xb = (size_t)b * 4096;
        float pi = acc[0][n][r] + bf2f(Xpt[xb + j]) + bi_;
        float pf = acc[1][n][r] + bf2f(Xpt[xb + 1024 + j]) + bf_;
        float pg = acc[2][n][r] + bf2f(Xpt[xb + 2048 + j]) + bg_;
        float po = acc[3][n][r] + bf2f(Xpt[xb + 3072 + j]) + bo_;
        float ig = sigm(pi), fg = sigm(pf), gg = tanh_f(pg), og = sigm(po);
        float c_new = fg * cst[(size_t)b * 1024 + j] + ig * gg;
        cst[(size_t)b * 1024 + j] = c_new;
        cn[r] = c_new;
        hn[r] = og * tanh_f(c_new);
        out_h[(size_t)b * 1024 + j] = hn[r];
      }
      unsigned long long hp = (unsigned long long)f2bf(hn[0]) |
                              ((unsigned long long)f2bf(hn[1]) << 16) |
                              ((unsigned long long)f2bf(hn[2]) << 32) |
                              ((unsigned long long)f2bf(hn[3]) << 48);
      *(unsigned long long*)&hT_next[(size_t)j * 1024 + bbase] = hp;
      if (t == 127) {
#pragma unroll
        for (int r = 0; r < 4; ++r) {
          int b = bbase + r;
          out[134217728ull + (size_t)b * 1024 + j] = hn[r];
          out[135266304ull + (size_t)b * 1024 + j] = cn[r];
        }
      }
    }

    // ---- publish: writeback my block's stores, then count ----
    __syncthreads();                                   // all stores in L2
    __builtin_amdgcn_fence(__ATOMIC_RELEASE, "agent"); // wbl2 per wave
    __syncthreads();                                   // every wave flushed
    if (tid == 0)
      __hip_atomic_fetch_add(&cnt[t * 16 + bj], 1u, __ATOMIC_RELAXED,
                             __HIP_MEMORY_SCOPE_AGENT);
  }
}

// ---------------- host ----------------
extern "C" void kernel_launch(void* const* d_in, const int* in_sizes, int n_in,
                              void* d_out, int out_size, void* d_ws, size_t ws_size,
                              hipStream_t stream) {
  const float* X   = (const float*)d_in[0];
  const float* Wii = (const float*)d_in[1];
  const float* Whi = (const float*)d_in[2];
  const float* bi  = (const float*)d_in[3];
  const float* Wif = (const float*)d_in[4];
  const float* Whf = (const float*)d_in[5];
  const float* bfv = (const float*)d_in[6];
  const float* Wig = (const float*)d_in[7];
  const float* Whg = (const float*)d_in[8];
  const float* bg  = (const float*)d_in[9];
  const float* Wio = (const float*)d_in[10];
  const float* Who = (const float*)d_in[11];
  const float* bo  = (const float*)d_in[12];
  float* out = (float*)d_out;

  char* wsp = (char*)d_ws;
  size_t off = 0;
  auto walloc = [&](size_t b) -> void* {
    void* p = wsp + off;
    off += (b + 255) & ~(size_t)255;
    return p;
  };
  unsigned short* WiT = (unsigned short*)walloc(4096ull * 1024 * 2);
  unsigned short* Wh  = (unsigned short*)walloc(4096ull * 1024 * 2);
  float* bias = (float*)walloc(4096 * 4);
  unsigned short* hT0 = (unsigned short*)walloc(1024ull * 1024 * 2);
  unsigned short* hT1 = (unsigned short*)walloc(1024ull * 1024 * 2);
  float* cbuf = (float*)walloc(1024ull * 1024 * 4);
  unsigned int* cnt = (unsigned int*)walloc(128 * 16 * 4);
  size_t fixed = off;

  long long avail = (long long)ws_size - (long long)fixed - (1ll << 20);
  int Tc = (int)(avail / (10ll << 20));   // 2MB Xbf + 8MB Xproj per step
  if (Tc < 1) Tc = 1;
  if (Tc > 128) Tc = 128;
  unsigned short* Xbf = (unsigned short*)walloc((size_t)Tc * 1024 * 1024 * 2);
  unsigned short* Xp  = (unsigned short*)walloc((size_t)Tc * 1024 * 4096 * 2);

  conv_wh_kernel<<<4096, 256, 0, stream>>>((const float4*)Whi, (const float4*)Whf,
                                           (const float4*)Whg, (const float4*)Who,
                                           (unsigned long long*)Wh);
  conv_wiT_kernel<<<1024, 256, 0, stream>>>(Wii, Wif, Wig, Wio, WiT);
  conv_bias_kernel<<<16, 256, 0, stream>>>(bi, bfv, bg, bo, bias);
  hipMemsetAsync(hT0, 0, 1024ull * 1024 * 2, stream);
  hipMemsetAsync(cbuf, 0, 1024ull * 1024 * 4, stream);
  hipMemsetAsync(cnt, 0, 128 * 16 * 4, stream);

  for (int t0 = 0; t0 < 128; t0 += Tc) {
    int tc = (128 - t0 < Tc) ? (128 - t0) : Tc;
    int n4 = tc * 262144;
    conv_x_kernel<<<n4 / 256, 256, 0, stream>>>(
        (const float4*)(X + (size_t)t0 * 1048576),
        (unsigned long long*)Xbf, n4);
    xproj_gemm_kernel<<<tc * 256, 256, 0, stream>>>(Xbf, WiT, Xp, tc * 1024);
    lstm_persist_kernel<<<256, 512, 0, stream>>>(
        Wh, hT0, hT1, Xp, bias, cbuf, out, cnt, t0, tc);
  }
}

// Round 4
// 4026.023 us; speedup vs baseline: 3.3109x; 3.3109x over previous
//
#include <hip/hip_runtime.h>
#include <cstdint>

typedef __attribute__((ext_vector_type(8))) short bf16x8;
typedef __attribute__((ext_vector_type(4))) float f32x4;

#define AS1 __attribute__((address_space(1)))
#define AS3 __attribute__((address_space(3)))

__device__ __forceinline__ unsigned short f2bf(float f) {
  unsigned int u = __builtin_bit_cast(unsigned int, f);
  return (unsigned short)((u + 0x7fffu + ((u >> 16) & 1u)) >> 16);
}
__device__ __forceinline__ float bf2f(unsigned short h) {
  unsigned int u = ((unsigned int)h) << 16;
  return __builtin_bit_cast(float, u);
}
__device__ __forceinline__ float sigm(float x) { return 1.f / (1.f + __expf(-x)); }
__device__ __forceinline__ float tanh_f(float x) {
  float e = __expf(2.f * x);          // inf-safe: e=inf -> 1, e=0 -> -1
  return 1.f - 2.f / (e + 1.f);
}
__device__ __forceinline__ void gload16(const void* g, void* l) {
  __builtin_amdgcn_global_load_lds((const AS1 unsigned int*)g, (AS3 unsigned int*)l, 16, 0, 0);
}
// XOR-swizzle within a [rows][64]-bf16 tile (T2; pre-swizzled global source +
// swizzled ds_read, linear LDS dest — rule #21).
__device__ __forceinline__ int swz(int e) { return e ^ (((e >> 6) & 7) << 3); }

// ---------------- setup / conversion kernels ----------------

__global__ __launch_bounds__(256) void conv_wh_kernel(
    const float4* __restrict__ w0, const float4* __restrict__ w1,
    const float4* __restrict__ w2, const float4* __restrict__ w3,
    unsigned long long* __restrict__ dst) {
  int i = blockIdx.x * 256 + threadIdx.x;           // 0 .. 1M-1 (float4 units)
  int g = i >> 18;                                  // 262144 float4 per matrix
  const float4* s = g == 0 ? w0 : g == 1 ? w1 : g == 2 ? w2 : w3;
  float4 v = s[i & 0x3FFFF];
  unsigned long long p = (unsigned long long)f2bf(v.x) |
                         ((unsigned long long)f2bf(v.y) << 16) |
                         ((unsigned long long)f2bf(v.z) << 32) |
                         ((unsigned long long)f2bf(v.w) << 48);
  dst[i] = p;
}

__global__ __launch_bounds__(256) void conv_wiT_kernel(
    const float* __restrict__ w0, const float* __restrict__ w1,
    const float* __restrict__ w2, const float* __restrict__ w3,
    unsigned short* __restrict__ dst) {
  __shared__ unsigned short ls[64][72];
  int bid = blockIdx.x;                 // 0..1023 : 4 gates x 16x16 tiles
  int g = bid >> 8;
  int t2 = bid & 255;
  int tj = t2 & 15, tk = t2 >> 4;
  const float* W = g == 0 ? w0 : g == 1 ? w1 : g == 2 ? w2 : w3;
  int k0 = tk * 64, j0 = tj * 64;
  int ty = threadIdx.x >> 6, tx = threadIdx.x & 63;
#pragma unroll
  for (int r = 0; r < 16; ++r) {
    int k = k0 + ty * 16 + r;
    ls[tx][ty * 16 + r] = f2bf(W[k * 1024 + j0 + tx]);  // ls[j_local][k_local]
  }
  __syncthreads();
#pragma unroll
  for (int r = 0; r < 16; ++r) {
    int jl = ty * 16 + r;
    dst[(size_t)(g * 1024 + j0 + jl) * 1024 + k0 + tx] = ls[jl][tx];
  }
}

__global__ __launch_bounds__(256) void conv_bias_kernel(
    const float* __restrict__ b0, const float* __restrict__ b1,
    const float* __restrict__ b2, const float* __restrict__ b3,
    float* __restrict__ dst) {
  int i = blockIdx.x * 256 + threadIdx.x;  // 0..4095
  const float* s = (i >> 10) == 0 ? b0 : (i >> 10) == 1 ? b1 : (i >> 10) == 2 ? b2 : b3;
  dst[i] = s[i & 1023];
}

__global__ __launch_bounds__(256) void conv_x_kernel(
    const float4* __restrict__ src, unsigned long long* __restrict__ dst, int n4) {
  int i = blockIdx.x * 256 + threadIdx.x;
  if (i < n4) {
    float4 v = src[i];
    dst[i] = (unsigned long long)f2bf(v.x) |
             ((unsigned long long)f2bf(v.y) << 16) |
             ((unsigned long long)f2bf(v.z) << 32) |
             ((unsigned long long)f2bf(v.w) << 48);
  }
}

// ---------------- input-projection GEMM ----------------
// m97 structure, 128x128 tile, BK=64, 4 waves (2x2). LB(256,3) targets
// 3 waves/SIMD. XCD-aware block swizzle (T1, bijective since nwg%8==0).
// Epilogue bounces C through LDS so global stores are full 16B lines
// (kills write-allocate over-fetch).
__global__ __launch_bounds__(256, 3) void xproj_gemm_kernel(
    const unsigned short* __restrict__ A,   // [Mc][1024]
    const unsigned short* __restrict__ Bt,  // [4096][1024]
    unsigned short* __restrict__ C,         // [Mc][4096]
    int Mc) {
  __shared__ __align__(16) char smem[34816];          // 34 KB union
  unsigned short* lsA = (unsigned short*)smem;        // [128*64]
  unsigned short* lsB = lsA + 8192;                   // [128*64]
  int nwg = gridDim.x;                    // tc*256, divisible by 8
  int cpx = nwg >> 3;
  int bxs = (blockIdx.x & 7) * cpx + (blockIdx.x >> 3);   // XCD-contiguous
  int bm = bxs >> 5, bn = bxs & 31;
  int m0 = bm * 128, n0 = bn * 128;
  int tid = threadIdx.x, w = tid >> 6, lane = tid & 63;
  int wm = w >> 1, wn = w & 1;
  int l15 = lane & 15, l4 = lane >> 4;

  f32x4 acc[4][4];
#pragma unroll
  for (int i = 0; i < 4; ++i)
#pragma unroll
    for (int j = 0; j < 4; ++j) acc[i][j] = (f32x4)0.f;

  for (int ks = 0; ks < 16; ++ks) {
    int kk = ks * 64;
    __syncthreads();   // everyone done reading previous tile
#pragma unroll
    for (int ld = 0; ld < 4; ++ld) {
      int cid = ld * 256 + tid;
      int r = cid >> 3, kc = (cid & 7) * 8;
      int sk = kk + (kc ^ ((r & 7) << 3));
      gload16(&A[(size_t)(m0 + r) * 1024 + sk], &lsA[(ld * 256 + w * 64) * 8]);
      gload16(&Bt[(size_t)(n0 + r) * 1024 + sk], &lsB[(ld * 256 + w * 64) * 8]);
    }
    __syncthreads();   // data ready (drains vmcnt)
    bf16x8 af[4][2], bfr[4][2];
#pragma unroll
    for (int cm = 0; cm < 4; ++cm)
#pragma unroll
      for (int kss = 0; kss < 2; ++kss) {
        int e = (wm * 64 + cm * 16 + l15) * 64 + kss * 32 + l4 * 8;
        af[cm][kss] = *(const bf16x8*)&lsA[swz(e)];
      }
#pragma unroll
    for (int cn = 0; cn < 4; ++cn)
#pragma unroll
      for (int kss = 0; kss < 2; ++kss) {
        int e = (wn * 64 + cn * 16 + l15) * 64 + kss * 32 + l4 * 8;
        bfr[cn][kss] = *(const bf16x8*)&lsB[swz(e)];
      }
    __builtin_amdgcn_s_setprio(1);
#pragma unroll
    for (int cm = 0; cm < 4; ++cm)
#pragma unroll
      for (int cn = 0; cn < 4; ++cn)
#pragma unroll
        for (int kss = 0; kss < 2; ++kss)
          acc[cm][cn] = __builtin_amdgcn_mfma_f32_16x16x32_bf16(
              af[cm][kss], bfr[cn][kss], acc[cm][cn], 0, 0, 0);
    __builtin_amdgcn_s_setprio(0);
  }

  // ---- epilogue: acc -> LDS (bf16) -> coalesced 16B global stores ----
  __syncthreads();
  unsigned short* lsC = (unsigned short*)smem;   // [128][136]
#pragma unroll
  for (int cm = 0; cm < 4; ++cm)
#pragma unroll
    for (int cn = 0; cn < 4; ++cn)
#pragma unroll
      for (int r = 0; r < 4; ++r) {
        int row = wm * 64 + cm * 16 + l4 * 4 + r;
        int col = wn * 64 + cn * 16 + l15;
        lsC[row * 136 + col] = f2bf(acc[cm][cn][r]);
      }
  __syncthreads();
#pragma unroll
  for (int u = 0; u < 8; ++u) {
    int chunk = u * 256 + tid;        // 0..2047 : 128 rows x 16 chunks of 16B
    int row = chunk >> 4, c8 = chunk & 15;
    bf16x8 v = *(const bf16x8*)&lsC[row * 136 + c8 * 8];
    *(bf16x8*)&C[(size_t)(m0 + row) * 4096 + n0 + c8 * 8] = v;
  }
}

// ---------------- fused LSTM step (per-step launch) ----------------
// Per block: tile (64 batch x 64 hidden) for ALL 4 gates. XCD-aware map:
// XCD x owns bb in {2x,2x+1}, all bj -> per-XCD set = 1MB Wh + 2MB hT (L2).
// 3-buffer, 2-deep prefetch, counted vmcnt (10/5/0), raw s_barriers (T3+T4).
// Epilogue operands (cst, Xp, bias) prefetched into registers BEFORE the
// K-loop: they are oldest in the vmcnt FIFO so the counted waits subsume
// them, hiding their L3 latency under the pipeline (T14 spirit).
__global__ __launch_bounds__(512) void lstm_step_kernel(
    const unsigned short* __restrict__ Wh,   // [4096][1024]
    const unsigned short* __restrict__ hT,   // [1024][1024]  hT[j][k]=h[k][j]
    const unsigned short* __restrict__ Xp,   // [1024][4096]  this step's x-proj
    const float* __restrict__ bias,          // [4096]
    float* __restrict__ cst,                 // [1024*1024] fp32 cell state
    float* __restrict__ out_h,               // d_out + t*1M
    float* __restrict__ out_ht,              // d_out + T*1M
    float* __restrict__ out_ct,              // d_out + T*1M + 1M
    unsigned short* __restrict__ hT_next,    // other hT buffer
    int isLast) {
  __shared__ unsigned short lsA[3][256 * 64];  // 4 gates x 64 rows x BK
  __shared__ unsigned short lsB[3][64 * 64];
  int bx = blockIdx.x;
  int xcd = bx & 7, idx = bx >> 3;             // block->XCD round-robin %8
  int bb = xcd * 2 + (idx & 1);                // XCD-local Wh slice
  int bj = idx >> 1;
  int b0 = bb * 64, j0 = bj * 64;
  int tid = threadIdx.x, w = tid >> 6, lane = tid & 63;
  int wm = w >> 1, wn = w & 1;
  int l15 = lane & 15, l4 = lane >> 4;
  int bbase = b0 + wm * 16 + l4 * 4;

  // ---- prefetch epilogue operands (issued first -> oldest in vmcnt FIFO) --
  float bias_pre[4][2];
  float c_pre[2][4];
  unsigned short xp_pre[4][2][4];
#pragma unroll
  for (int n = 0; n < 2; ++n) {
    int j = j0 + wn * 32 + n * 16 + l15;
#pragma unroll
    for (int g = 0; g < 4; ++g) bias_pre[g][n] = bias[g * 1024 + j];
#pragma unroll
    for (int r = 0; r < 4; ++r) {
      c_pre[n][r] = cst[(size_t)(bbase + r) * 1024 + j];
#pragma unroll
      for (int g = 0; g < 4; ++g)
        xp_pre[g][n][r] = Xp[(size_t)(bbase + r) * 4096 + g * 1024 + j];
    }
  }

  f32x4 acc[4][2];
#pragma unroll
  for (int g = 0; g < 4; ++g)
#pragma unroll
    for (int n = 0; n < 2; ++n) acc[g][n] = (f32x4)0.f;

  auto stage = [&](int buf, int kk) {          // 5 gload16 per thread
#pragma unroll
    for (int ld = 0; ld < 4; ++ld) {
      int cid = ld * 512 + tid;
      int r = cid >> 3, kc = (cid & 7) * 8;    // r: 0..255 local row
      int sk = kk + (kc ^ ((r & 7) << 3));
      int grow = (r >> 6) * 1024 + b0 + (r & 63);
      gload16(&Wh[(size_t)grow * 1024 + sk], &lsA[buf][(ld * 512 + w * 64) * 8]);
    }
    {
      int r = tid >> 3, kc = (tid & 7) * 8;    // r: 0..63
      int sk = kk + (kc ^ ((r & 7) << 3));
      gload16(&hT[(size_t)(j0 + r) * 1024 + sk], &lsB[buf][w * 512]);
    }
  };
  auto compute = [&](int buf) {
    bf16x8 af[4][2], bfr[2][2];
#pragma unroll
    for (int g = 0; g < 4; ++g)
#pragma unroll
      for (int kss = 0; kss < 2; ++kss) {
        int e = (g * 64 + wm * 16 + l15) * 64 + kss * 32 + l4 * 8;
        af[g][kss] = *(const bf16x8*)&lsA[buf][swz(e)];
      }
#pragma unroll
    for (int n = 0; n < 2; ++n)
#pragma unroll
      for (int kss = 0; kss < 2; ++kss) {
        int e = (wn * 32 + n * 16 + l15) * 64 + kss * 32 + l4 * 8;
        bfr[n][kss] = *(const bf16x8*)&lsB[buf][swz(e)];
      }
    __builtin_amdgcn_s_setprio(1);
#pragma unroll
    for (int g = 0; g < 4; ++g)
#pragma unroll
      for (int n = 0; n < 2; ++n)
#pragma unroll
        for (int kss = 0; kss < 2; ++kss)
          acc[g][n] = __builtin_amdgcn_mfma_f32_16x16x32_bf16(
              af[g][kss], bfr[n][kss], acc[g][n], 0, 0, 0);
    __builtin_amdgcn_s_setprio(0);
  };

  // prologue: 2 stages in flight (10 staging loads + 48 prefetch outstanding)
  stage(0, 0);
  stage(1, 64);
#pragma unroll
  for (int i = 0; i < 16; ++i) {
    if (i + 2 < 16) stage((i + 2) % 3, (i + 2) * 64);  // issue-early
    // wait for stage i (and, the first time, the epilogue prefetches — they
    // are older); newer stages stay in flight across the barrier
    if (i < 14)        asm volatile("s_waitcnt vmcnt(10)" ::: "memory");
    else if (i == 14)  asm volatile("s_waitcnt vmcnt(5)" ::: "memory");
    else               asm volatile("s_waitcnt vmcnt(0)" ::: "memory");
    __builtin_amdgcn_sched_barrier(0);
    __builtin_amdgcn_s_barrier();              // all waves' stage(i) landed
    __builtin_amdgcn_sched_barrier(0);
    compute(i % 3);
    asm volatile("s_waitcnt lgkmcnt(0)" ::: "memory");  // my ds_reads retired
    __builtin_amdgcn_sched_barrier(0);
    __builtin_amdgcn_s_barrier();              // buf (i)%3 free for restage
    __builtin_amdgcn_sched_barrier(0);
  }

  // epilogue: gates + cell/hidden update (all operands already in registers)
#pragma unroll
  for (int n = 0; n < 2; ++n) {
    int j = j0 + wn * 32 + n * 16 + l15;
    float hn[4], cn[4];
#pragma unroll
    for (int r = 0; r < 4; ++r) {
      int b = bbase + r;
      float pi = acc[0][n][r] + bf2f(xp_pre[0][n][r]) + bias_pre[0][n];
      float pf = acc[1][n][r] + bf2f(xp_pre[1][n][r]) + bias_pre[1][n];
      float pg = acc[2][n][r] + bf2f(xp_pre[2][n][r]) + bias_pre[2][n];
      float po = acc[3][n][r] + bf2f(xp_pre[3][n][r]) + bias_pre[3][n];
      float ig = sigm(pi), fg = sigm(pf), gg = tanh_f(pg), og = sigm(po);
      float c_new = fg * c_pre[n][r] + ig * gg;
      cst[(size_t)b * 1024 + j] = c_new;
      cn[r] = c_new;
      hn[r] = og * tanh_f(c_new);
      out_h[(size_t)b * 1024 + j] = hn[r];
    }
    unsigned long long hp = (unsigned long long)f2bf(hn[0]) |
                            ((unsigned long long)f2bf(hn[1]) << 16) |
                            ((unsigned long long)f2bf(hn[2]) << 32) |
                            ((unsigned long long)f2bf(hn[3]) << 48);
    *(unsigned long long*)&hT_next[(size_t)j * 1024 + bbase] = hp;
    if (isLast) {
#pragma unroll
      for (int r = 0; r < 4; ++r) {
        int b = bbase + r;
        out_ht[(size_t)b * 1024 + j] = hn[r];
        out_ct[(size_t)b * 1024 + j] = cn[r];
      }
    }
  }
}

// ---------------- host ----------------
extern "C" void kernel_launch(void* const* d_in, const int* in_sizes, int n_in,
                              void* d_out, int out_size, void* d_ws, size_t ws_size,
                              hipStream_t stream) {
  const float* X   = (const float*)d_in[0];
  const float* Wii = (const float*)d_in[1];
  const float* Whi = (const float*)d_in[2];
  const float* bi  = (const float*)d_in[3];
  const float* Wif = (const float*)d_in[4];
  const float* Whf = (const float*)d_in[5];
  const float* bfv = (const float*)d_in[6];
  const float* Wig = (const float*)d_in[7];
  const float* Whg = (const float*)d_in[8];
  const float* bg  = (const float*)d_in[9];
  const float* Wio = (const float*)d_in[10];
  const float* Who = (const float*)d_in[11];
  const float* bo  = (const float*)d_in[12];
  float* out = (float*)d_out;

  char* wsp = (char*)d_ws;
  size_t off = 0;
  auto walloc = [&](size_t b) -> void* {
    void* p = wsp + off;
    off += (b + 255) & ~(size_t)255;
    return p;
  };
  unsigned short* WiT = (unsigned short*)walloc(4096ull * 1024 * 2);
  unsigned short* Wh  = (unsigned short*)walloc(4096ull * 1024 * 2);
  float* bias = (float*)walloc(4096 * 4);
  unsigned short* hT0 = (unsigned short*)walloc(1024ull * 1024 * 2);
  unsigned short* hT1 = (unsigned short*)walloc(1024ull * 1024 * 2);
  float* cbuf = (float*)walloc(1024ull * 1024 * 4);
  size_t fixed = off;

  long long avail = (long long)ws_size - (long long)fixed - (1ll << 20);
  int Tc = (int)(avail / (10ll << 20));   // 2MB Xbf + 8MB Xproj per step
  if (Tc < 1) Tc = 1;
  if (Tc > 128) Tc = 128;
  unsigned short* Xbf = (unsigned short*)walloc((size_t)Tc * 1024 * 1024 * 2);
  unsigned short* Xp  = (unsigned short*)walloc((size_t)Tc * 1024 * 4096 * 2);

  conv_wh_kernel<<<4096, 256, 0, stream>>>((const float4*)Whi, (const float4*)Whf,
                                           (const float4*)Whg, (const float4*)Who,
                                           (unsigned long long*)Wh);
  conv_wiT_kernel<<<1024, 256, 0, stream>>>(Wii, Wif, Wig, Wio, WiT);
  conv_bias_kernel<<<16, 256, 0, stream>>>(bi, bfv, bg, bo, bias);
  hipMemsetAsync(hT0, 0, 1024ull * 1024 * 2, stream);
  hipMemsetAsync(cbuf, 0, 1024ull * 1024 * 4, stream);

  for (int t0 = 0; t0 < 128; t0 += Tc) {
    int tc = (128 - t0 < Tc) ? (128 - t0) : Tc;
    int n4 = tc * 262144;
    conv_x_kernel<<<n4 / 256, 256, 0, stream>>>(
        (const float4*)(X + (size_t)t0 * 1048576),
        (unsigned long long*)Xbf, n4);
    xproj_gemm_kernel<<<tc * 256, 256, 0, stream>>>(Xbf, WiT, Xp, tc * 1024);
    for (int i = 0; i < tc; ++i) {
      int t = t0 + i;
      lstm_step_kernel<<<256, 512, 0, stream>>>(
          Wh, (t & 1) ? hT1 : hT0,
          Xp + (size_t)i * 1024 * 4096,
          bias, cbuf,
          out + (size_t)t * 1048576,
          out + 134217728ull,
          out + 135266304ull,
          (t & 1) ? hT0 : hT1,
          (t == 127) ? 1 : 0);
    }
  }
}

// Round 5
// 3813.902 us; speedup vs baseline: 3.4950x; 1.0556x over previous
//
#include <hip/hip_runtime.h>
#include <cstdint>

typedef __attribute__((ext_vector_type(8))) short bf16x8;
typedef __attribute__((ext_vector_type(4))) float f32x4;

#define AS1 __attribute__((address_space(1)))
#define AS3 __attribute__((address_space(3)))

__device__ __forceinline__ unsigned short f2bf(float f) {
  unsigned int u = __builtin_bit_cast(unsigned int, f);
  return (unsigned short)((u + 0x7fffu + ((u >> 16) & 1u)) >> 16);
}
__device__ __forceinline__ float bf2f(unsigned short h) {
  unsigned int u = ((unsigned int)h) << 16;
  return __builtin_bit_cast(float, u);
}
__device__ __forceinline__ float sigm(float x) { return 1.f / (1.f + __expf(-x)); }
__device__ __forceinline__ float tanh_f(float x) {
  float e = __expf(2.f * x);          // inf-safe: e=inf -> 1, e=0 -> -1
  return 1.f - 2.f / (e + 1.f);
}
__device__ __forceinline__ void gload16(const void* g, void* l) {
  __builtin_amdgcn_global_load_lds((const AS1 unsigned int*)g, (AS3 unsigned int*)l, 16, 0, 0);
}
// XOR-swizzle within a [rows][64]-bf16 tile (T2; pre-swizzled global source +
// swizzled ds_read, linear LDS dest — rule #21).
__device__ __forceinline__ int swz(int e) { return e ^ (((e >> 6) & 7) << 3); }

// ---------------- setup / conversion kernels ----------------

__global__ __launch_bounds__(256) void conv_wh_kernel(
    const float4* __restrict__ w0, const float4* __restrict__ w1,
    const float4* __restrict__ w2, const float4* __restrict__ w3,
    unsigned long long* __restrict__ dst) {
  int i = blockIdx.x * 256 + threadIdx.x;           // 0 .. 1M-1 (float4 units)
  int g = i >> 18;                                  // 262144 float4 per matrix
  const float4* s = g == 0 ? w0 : g == 1 ? w1 : g == 2 ? w2 : w3;
  float4 v = s[i & 0x3FFFF];
  unsigned long long p = (unsigned long long)f2bf(v.x) |
                         ((unsigned long long)f2bf(v.y) << 16) |
                         ((unsigned long long)f2bf(v.z) << 32) |
                         ((unsigned long long)f2bf(v.w) << 48);
  dst[i] = p;
}

__global__ __launch_bounds__(256) void conv_wiT_kernel(
    const float* __restrict__ w0, const float* __restrict__ w1,
    const float* __restrict__ w2, const float* __restrict__ w3,
    unsigned short* __restrict__ dst) {
  __shared__ unsigned short ls[64][72];
  int bid = blockIdx.x;                 // 0..1023 : 4 gates x 16x16 tiles
  int g = bid >> 8;
  int t2 = bid & 255;
  int tj = t2 & 15, tk = t2 >> 4;
  const float* W = g == 0 ? w0 : g == 1 ? w1 : g == 2 ? w2 : w3;
  int k0 = tk * 64, j0 = tj * 64;
  int ty = threadIdx.x >> 6, tx = threadIdx.x & 63;
#pragma unroll
  for (int r = 0; r < 16; ++r) {
    int k = k0 + ty * 16 + r;
    ls[tx][ty * 16 + r] = f2bf(W[k * 1024 + j0 + tx]);  // ls[j_local][k_local]
  }
  __syncthreads();
#pragma unroll
  for (int r = 0; r < 16; ++r) {
    int jl = ty * 16 + r;
    dst[(size_t)(g * 1024 + j0 + jl) * 1024 + k0 + tx] = ls[jl][tx];
  }
}

__global__ __launch_bounds__(256) void conv_bias_kernel(
    const float* __restrict__ b0, const float* __restrict__ b1,
    const float* __restrict__ b2, const float* __restrict__ b3,
    float* __restrict__ dst) {
  int i = blockIdx.x * 256 + threadIdx.x;  // 0..4095
  const float* s = (i >> 10) == 0 ? b0 : (i >> 10) == 1 ? b1 : (i >> 10) == 2 ? b2 : b3;
  dst[i] = s[i & 1023];
}

__global__ __launch_bounds__(256) void conv_x_kernel(
    const float4* __restrict__ src, unsigned long long* __restrict__ dst, int n4) {
  int i = blockIdx.x * 256 + threadIdx.x;
  if (i < n4) {
    float4 v = src[i];
    dst[i] = (unsigned long long)f2bf(v.x) |
             ((unsigned long long)f2bf(v.y) << 16) |
             ((unsigned long long)f2bf(v.z) << 32) |
             ((unsigned long long)f2bf(v.w) << 48);
  }
}

// ---------------- input-projection GEMM ----------------
// m97 structure, 128x128 tile, BK=64, 4 waves (2x2), LB(256,3).
// Block map: XCD x owns bn in {4x..4x+3} for ALL bm -> per-XCD B working
// set = 1MB, L2-resident forever; the 4 consecutive-i blocks of one bm
// share the A-panel in-window. Epilogue bounces C through LDS (stride 144:
// conflict-free) for full-16B global stores.
__global__ __launch_bounds__(256, 3) void xproj_gemm_kernel(
    const unsigned short* __restrict__ A,   // [Mc][1024]
    const unsigned short* __restrict__ Bt,  // [4096][1024]
    unsigned short* __restrict__ C,         // [Mc][4096]
    int Mc) {
  __shared__ __align__(16) char smem[36864];          // 36 KB union
  unsigned short* lsA = (unsigned short*)smem;        // [128*64]
  unsigned short* lsB = lsA + 8192;                   // [128*64]
  int xcd = blockIdx.x & 7;               // HW round-robin block->XCD
  int i5 = blockIdx.x >> 3;
  int bn = xcd * 4 + (i5 & 3);            // 4 B-panels per XCD (1MB, L2)
  int bm = i5 >> 2;
  int m0 = bm * 128, n0 = bn * 128;
  int tid = threadIdx.x, w = tid >> 6, lane = tid & 63;
  int wm = w >> 1, wn = w & 1;
  int l15 = lane & 15, l4 = lane >> 4;

  f32x4 acc[4][4];
#pragma unroll
  for (int i = 0; i < 4; ++i)
#pragma unroll
    for (int j = 0; j < 4; ++j) acc[i][j] = (f32x4)0.f;

  for (int ks = 0; ks < 16; ++ks) {
    int kk = ks * 64;
    __syncthreads();   // everyone done reading previous tile
#pragma unroll
    for (int ld = 0; ld < 4; ++ld) {
      int cid = ld * 256 + tid;
      int r = cid >> 3, kc = (cid & 7) * 8;
      int sk = kk + (kc ^ ((r & 7) << 3));
      gload16(&A[(size_t)(m0 + r) * 1024 + sk], &lsA[(ld * 256 + w * 64) * 8]);
      gload16(&Bt[(size_t)(n0 + r) * 1024 + sk], &lsB[(ld * 256 + w * 64) * 8]);
    }
    __syncthreads();   // data ready (drains vmcnt)
    bf16x8 af[4][2], bfr[4][2];
#pragma unroll
    for (int cm = 0; cm < 4; ++cm)
#pragma unroll
      for (int kss = 0; kss < 2; ++kss) {
        int e = (wm * 64 + cm * 16 + l15) * 64 + kss * 32 + l4 * 8;
        af[cm][kss] = *(const bf16x8*)&lsA[swz(e)];
      }
#pragma unroll
    for (int cn = 0; cn < 4; ++cn)
#pragma unroll
      for (int kss = 0; kss < 2; ++kss) {
        int e = (wn * 64 + cn * 16 + l15) * 64 + kss * 32 + l4 * 8;
        bfr[cn][kss] = *(const bf16x8*)&lsB[swz(e)];
      }
    __builtin_amdgcn_s_setprio(1);
#pragma unroll
    for (int cm = 0; cm < 4; ++cm)
#pragma unroll
      for (int cn = 0; cn < 4; ++cn)
#pragma unroll
        for (int kss = 0; kss < 2; ++kss)
          acc[cm][cn] = __builtin_amdgcn_mfma_f32_16x16x32_bf16(
              af[cm][kss], bfr[cn][kss], acc[cm][cn], 0, 0, 0);
    __builtin_amdgcn_s_setprio(0);
  }

  // ---- epilogue: acc -> LDS (bf16) -> coalesced 16B global stores ----
  __syncthreads();
  unsigned short* lsC = (unsigned short*)smem;   // [128][144]
#pragma unroll
  for (int cm = 0; cm < 4; ++cm)
#pragma unroll
    for (int cn = 0; cn < 4; ++cn)
#pragma unroll
      for (int r = 0; r < 4; ++r) {
        int row = wm * 64 + cm * 16 + l4 * 4 + r;
        int col = wn * 64 + cn * 16 + l15;
        lsC[row * 144 + col] = f2bf(acc[cm][cn][r]);
      }
  __syncthreads();
#pragma unroll
  for (int u = 0; u < 8; ++u) {
    int chunk = u * 256 + tid;        // 0..2047 : 128 rows x 16 chunks of 16B
    int row = chunk >> 4, c8 = chunk & 15;
    bf16x8 v = *(const bf16x8*)&lsC[row * 144 + c8 * 8];
    *(bf16x8*)&C[(size_t)(m0 + row) * 4096 + n0 + c8 * 8] = v;
  }
}

// ---------------- fused LSTM step (per-step launch) ----------------
// Per block: tile (64 batch x 64 hidden) for ALL 4 gates. XCD-aware map:
// XCD x owns bb in {2x,2x+1}, all bj -> per-XCD set = 1MB Wh + 2MB hT (L2).
// SINGLE-barrier 3-buffer pipeline: per iter {vmcnt(5); bar; stage(it+2);
// compute(it); lgkmcnt(0)}. The one barrier certifies both "stage(it)
// landed everywhere" (each wave's vmcnt precedes it) and "compute(it-1)
// reads retired everywhere" (each wave's lgkmcnt(0) precedes it) — exactly
// what stage(it+2)'s overwrite of buf (it-1)%3 requires. 16 barriers/step.
__global__ __launch_bounds__(512) void lstm_step_kernel(
    const unsigned short* __restrict__ Wh,   // [4096][1024]
    const unsigned short* __restrict__ hT,   // [1024][1024]  hT[j][k]=h[k][j]
    const unsigned short* __restrict__ Xp,   // [1024][4096]  this step's x-proj
    const float* __restrict__ bias,          // [4096]
    float* __restrict__ cst,                 // [1024*1024] fp32 cell state
    float* __restrict__ out_h,               // d_out + t*1M
    float* __restrict__ out_ht,              // d_out + T*1M
    float* __restrict__ out_ct,              // d_out + T*1M + 1M
    unsigned short* __restrict__ hT_next,    // other hT buffer
    int isLast) {
  __shared__ unsigned short lsA[3][256 * 64];  // 4 gates x 64 rows x BK
  __shared__ unsigned short lsB[3][64 * 64];
  int bx = blockIdx.x;
  int xcd = bx & 7, idx = bx >> 3;             // block->XCD round-robin %8
  int bb = xcd * 2 + (idx & 1);                // XCD-local Wh slice
  int bj = idx >> 1;
  int b0 = bb * 64, j0 = bj * 64;
  int tid = threadIdx.x, w = tid >> 6, lane = tid & 63;
  int wm = w >> 1, wn = w & 1;
  int l15 = lane & 15, l4 = lane >> 4;
  int bbase = b0 + wm * 16 + l4 * 4;

  // ---- prefetch epilogue operands (issued first -> oldest in vmcnt FIFO;
  //      it0's vmcnt(5) drains them along with stage(0)) ----
  float bias_pre[4][2];
  float c_pre[2][4];
  unsigned short xp_pre[4][2][4];
#pragma unroll
  for (int n = 0; n < 2; ++n) {
    int j = j0 + wn * 32 + n * 16 + l15;
#pragma unroll
    for (int g = 0; g < 4; ++g) bias_pre[g][n] = bias[g * 1024 + j];
#pragma unroll
    for (int r = 0; r < 4; ++r) {
      c_pre[n][r] = cst[(size_t)(bbase + r) * 1024 + j];
#pragma unroll
      for (int g = 0; g < 4; ++g)
        xp_pre[g][n][r] = Xp[(size_t)(bbase + r) * 4096 + g * 1024 + j];
    }
  }

  f32x4 acc[4][2];
#pragma unroll
  for (int g = 0; g < 4; ++g)
#pragma unroll
    for (int n = 0; n < 2; ++n) acc[g][n] = (f32x4)0.f;

  auto stage = [&](int buf, int kk) {          // 5 gload16 per thread
#pragma unroll
    for (int ld = 0; ld < 4; ++ld) {
      int cid = ld * 512 + tid;
      int r = cid >> 3, kc = (cid & 7) * 8;    // r: 0..255 local row
      int sk = kk + (kc ^ ((r & 7) << 3));
      int grow = (r >> 6) * 1024 + b0 + (r & 63);
      gload16(&Wh[(size_t)grow * 1024 + sk], &lsA[buf][(ld * 512 + w * 64) * 8]);
    }
    {
      int r = tid >> 3, kc = (tid & 7) * 8;    // r: 0..63
      int sk = kk + (kc ^ ((r & 7) << 3));
      gload16(&hT[(size_t)(j0 + r) * 1024 + sk], &lsB[buf][w * 512]);
    }
  };
  auto compute = [&](int buf) {
    bf16x8 af[4][2], bfr[2][2];
#pragma unroll
    for (int g = 0; g < 4; ++g)
#pragma unroll
      for (int kss = 0; kss < 2; ++kss) {
        int e = (g * 64 + wm * 16 + l15) * 64 + kss * 32 + l4 * 8;
        af[g][kss] = *(const bf16x8*)&lsA[buf][swz(e)];
      }
#pragma unroll
    for (int n = 0; n < 2; ++n)
#pragma unroll
      for (int kss = 0; kss < 2; ++kss) {
        int e = (wn * 32 + n * 16 + l15) * 64 + kss * 32 + l4 * 8;
        bfr[n][kss] = *(const bf16x8*)&lsB[buf][swz(e)];
      }
    __builtin_amdgcn_s_setprio(1);
#pragma unroll
    for (int g = 0; g < 4; ++g)
#pragma unroll
      for (int n = 0; n < 2; ++n)
#pragma unroll
        for (int kss = 0; kss < 2; ++kss)
          acc[g][n] = __builtin_amdgcn_mfma_f32_16x16x32_bf16(
              af[g][kss], bfr[n][kss], acc[g][n], 0, 0, 0);
    __builtin_amdgcn_s_setprio(0);
  };

  // prologue: 2 stages in flight
  stage(0, 0);
  stage(1, 64);
#pragma unroll
  for (int it = 0; it < 16; ++it) {
    // my stage(it) landed (leaves stage(it+1)'s 5 loads in flight)
    if (it < 15) asm volatile("s_waitcnt vmcnt(5)" ::: "memory");
    else         asm volatile("s_waitcnt vmcnt(0)" ::: "memory");
    __builtin_amdgcn_sched_barrier(0);
    __builtin_amdgcn_s_barrier();     // stage(it) landed + prev reads retired
    __builtin_amdgcn_sched_barrier(0);
    if (it + 2 < 16) stage((it + 2) % 3, (it + 2) * 64);  // overwrite safe now
    compute(it % 3);
    asm volatile("s_waitcnt lgkmcnt(0)" ::: "memory");    // my ds_reads done
    __builtin_amdgcn_sched_barrier(0);
  }

  // epilogue: gates + cell/hidden update (operands already in registers)
#pragma unroll
  for (int n = 0; n < 2; ++n) {
    int j = j0 + wn * 32 + n * 16 + l15;
    float hn[4], cn[4];
#pragma unroll
    for (int r = 0; r < 4; ++r) {
      int b = bbase + r;
      float pi = acc[0][n][r] + bf2f(xp_pre[0][n][r]) + bias_pre[0][n];
      float pf = acc[1][n][r] + bf2f(xp_pre[1][n][r]) + bias_pre[1][n];
      float pg = acc[2][n][r] + bf2f(xp_pre[2][n][r]) + bias_pre[2][n];
      float po = acc[3][n][r] + bf2f(xp_pre[3][n][r]) + bias_pre[3][n];
      float ig = sigm(pi), fg = sigm(pf), gg = tanh_f(pg), og = sigm(po);
      float c_new = fg * c_pre[n][r] + ig * gg;
      cst[(size_t)b * 1024 + j] = c_new;
      cn[r] = c_new;
      hn[r] = og * tanh_f(c_new);
      out_h[(size_t)b * 1024 + j] = hn[r];
    }
    unsigned long long hp = (unsigned long long)f2bf(hn[0]) |
                            ((unsigned long long)f2bf(hn[1]) << 16) |
                            ((unsigned long long)f2bf(hn[2]) << 32) |
                            ((unsigned long long)f2bf(hn[3]) << 48);
    *(unsigned long long*)&hT_next[(size_t)j * 1024 + bbase] = hp;
    if (isLast) {
#pragma unroll
      for (int r = 0; r < 4; ++r) {
        int b = bbase + r;
        out_ht[(size_t)b * 1024 + j] = hn[r];
        out_ct[(size_t)b * 1024 + j] = cn[r];
      }
    }
  }
}

// ---------------- host ----------------
extern "C" void kernel_launch(void* const* d_in, const int* in_sizes, int n_in,
                              void* d_out, int out_size, void* d_ws, size_t ws_size,
                              hipStream_t stream) {
  const float* X   = (const float*)d_in[0];
  const float* Wii = (const float*)d_in[1];
  const float* Whi = (const float*)d_in[2];
  const float* bi  = (const float*)d_in[3];
  const float* Wif = (const float*)d_in[4];
  const float* Whf = (const float*)d_in[5];
  const float* bfv = (const float*)d_in[6];
  const float* Wig = (const float*)d_in[7];
  const float* Whg = (const float*)d_in[8];
  const float* bg  = (const float*)d_in[9];
  const float* Wio = (const float*)d_in[10];
  const float* Who = (const float*)d_in[11];
  const float* bo  = (const float*)d_in[12];
  float* out = (float*)d_out;

  char* wsp = (char*)d_ws;
  size_t off = 0;
  auto walloc = [&](size_t b) -> void* {
    void* p = wsp + off;
    off += (b + 255) & ~(size_t)255;
    return p;
  };
  unsigned short* WiT = (unsigned short*)walloc(4096ull * 1024 * 2);
  unsigned short* Wh  = (unsigned short*)walloc(4096ull * 1024 * 2);
  float* bias = (float*)walloc(4096 * 4);
  unsigned short* hT0 = (unsigned short*)walloc(1024ull * 1024 * 2);
  unsigned short* hT1 = (unsigned short*)walloc(1024ull * 1024 * 2);
  float* cbuf = (float*)walloc(1024ull * 1024 * 4);
  size_t fixed = off;

  long long avail = (long long)ws_size - (long long)fixed - (1ll << 20);
  int Tc = (int)(avail / (10ll << 20));   // 2MB Xbf + 8MB Xproj per step
  if (Tc < 1) Tc = 1;
  if (Tc > 128) Tc = 128;
  unsigned short* Xbf = (unsigned short*)walloc((size_t)Tc * 1024 * 1024 * 2);
  unsigned short* Xp  = (unsigned short*)walloc((size_t)Tc * 1024 * 4096 * 2);

  conv_wh_kernel<<<4096, 256, 0, stream>>>((const float4*)Whi, (const float4*)Whf,
                                           (const float4*)Whg, (const float4*)Who,
                                           (unsigned long long*)Wh);
  conv_wiT_kernel<<<1024, 256, 0, stream>>>(Wii, Wif, Wig, Wio, WiT);
  conv_bias_kernel<<<16, 256, 0, stream>>>(bi, bfv, bg, bo, bias);
  hipMemsetAsync(hT0, 0, 1024ull * 1024 * 2, stream);
  hipMemsetAsync(cbuf, 0, 1024ull * 1024 * 4, stream);

  for (int t0 = 0; t0 < 128; t0 += Tc) {
    int tc = (128 - t0 < Tc) ? (128 - t0) : Tc;
    int n4 = tc * 262144;
    conv_x_kernel<<<n4 / 256, 256, 0, stream>>>(
        (const float4*)(X + (size_t)t0 * 1048576),
        (unsigned long long*)Xbf, n4);
    xproj_gemm_kernel<<<tc * 256, 256, 0, stream>>>(Xbf, WiT, Xp, tc * 1024);
    for (int i = 0; i < tc; ++i) {
      int t = t0 + i;
      lstm_step_kernel<<<256, 512, 0, stream>>>(
          Wh, (t & 1) ? hT1 : hT0,
          Xp + (size_t)i * 1024 * 4096,
          bias, cbuf,
          out + (size_t)t * 1048576,
          out + 134217728ull,
          out + 135266304ull,
          (t & 1) ? hT0 : hT1,
          (t == 127) ? 1 : 0);
    }
  }
}

// Round 6
// 3597.152 us; speedup vs baseline: 3.7056x; 1.0603x over previous
//
#include <hip/hip_runtime.h>
#include <cstdint>

typedef __attribute__((ext_vector_type(8))) short bf16x8;
typedef __attribute__((ext_vector_type(4))) float f32x4;

#define AS1 __attribute__((address_space(1)))
#define AS3 __attribute__((address_space(3)))

__device__ __forceinline__ unsigned short f2bf(float f) {
  unsigned int u = __builtin_bit_cast(unsigned int, f);
  return (unsigned short)((u + 0x7fffu + ((u >> 16) & 1u)) >> 16);
}
__device__ __forceinline__ float bf2f(unsigned short h) {
  unsigned int u = ((unsigned int)h) << 16;
  return __builtin_bit_cast(float, u);
}
__device__ __forceinline__ float sigm(float x) { return 1.f / (1.f + __expf(-x)); }
__device__ __forceinline__ float tanh_f(float x) {
  float e = __expf(2.f * x);          // inf-safe: e=inf -> 1, e=0 -> -1
  return 1.f - 2.f / (e + 1.f);
}
__device__ __forceinline__ void gload16(const void* g, void* l) {
  __builtin_amdgcn_global_load_lds((const AS1 unsigned int*)g, (AS3 unsigned int*)l, 16, 0, 0);
}
// XOR-swizzle within a [rows][64]-bf16 tile (T2; pre-swizzled global source +
// swizzled ds_read, linear LDS dest — rule #21).
__device__ __forceinline__ int swz(int e) { return e ^ (((e >> 6) & 7) << 3); }

// ---------------- setup / conversion kernels ----------------

__global__ __launch_bounds__(256) void conv_wh_kernel(
    const float4* __restrict__ w0, const float4* __restrict__ w1,
    const float4* __restrict__ w2, const float4* __restrict__ w3,
    unsigned long long* __restrict__ dst) {
  int i = blockIdx.x * 256 + threadIdx.x;           // 0 .. 1M-1 (float4 units)
  int g = i >> 18;                                  // 262144 float4 per matrix
  const float4* s = g == 0 ? w0 : g == 1 ? w1 : g == 2 ? w2 : w3;
  float4 v = s[i & 0x3FFFF];
  unsigned long long p = (unsigned long long)f2bf(v.x) |
                         ((unsigned long long)f2bf(v.y) << 16) |
                         ((unsigned long long)f2bf(v.z) << 32) |
                         ((unsigned long long)f2bf(v.w) << 48);
  dst[i] = p;
}

__global__ __launch_bounds__(256) void conv_wiT_kernel(
    const float* __restrict__ w0, const float* __restrict__ w1,
    const float* __restrict__ w2, const float* __restrict__ w3,
    unsigned short* __restrict__ dst) {
  __shared__ unsigned short ls[64][72];
  int bid = blockIdx.x;                 // 0..1023 : 4 gates x 16x16 tiles
  int g = bid >> 8;
  int t2 = bid & 255;
  int tj = t2 & 15, tk = t2 >> 4;
  const float* W = g == 0 ? w0 : g == 1 ? w1 : g == 2 ? w2 : w3;
  int k0 = tk * 64, j0 = tj * 64;
  int ty = threadIdx.x >> 6, tx = threadIdx.x & 63;
#pragma unroll
  for (int r = 0; r < 16; ++r) {
    int k = k0 + ty * 16 + r;
    ls[tx][ty * 16 + r] = f2bf(W[k * 1024 + j0 + tx]);  // ls[j_local][k_local]
  }
  __syncthreads();
#pragma unroll
  for (int r = 0; r < 16; ++r) {
    int jl = ty * 16 + r;
    dst[(size_t)(g * 1024 + j0 + jl) * 1024 + k0 + tx] = ls[jl][tx];
  }
}

__global__ __launch_bounds__(256) void conv_bias_kernel(
    const float* __restrict__ b0, const float* __restrict__ b1,
    const float* __restrict__ b2, const float* __restrict__ b3,
    float* __restrict__ dst) {
  int i = blockIdx.x * 256 + threadIdx.x;  // 0..4095
  const float* s = (i >> 10) == 0 ? b0 : (i >> 10) == 1 ? b1 : (i >> 10) == 2 ? b2 : b3;
  dst[i] = s[i & 1023];
}

__global__ __launch_bounds__(256) void conv_x_kernel(
    const float4* __restrict__ src, unsigned long long* __restrict__ dst, int n4) {
  int i = blockIdx.x * 256 + threadIdx.x;
  if (i < n4) {
    float4 v = src[i];
    dst[i] = (unsigned long long)f2bf(v.x) |
             ((unsigned long long)f2bf(v.y) << 16) |
             ((unsigned long long)f2bf(v.z) << 32) |
             ((unsigned long long)f2bf(v.w) << 48);
  }
}

// ---------------- input-projection GEMM ----------------
// m97 structure, 128x128 tile, BK=64, 4 waves (2x2), LB(256,3).
// Block map: XCD x owns bn in {4x..4x+3} for ALL bm -> per-XCD B working
// set = 1MB, L2-resident. Epilogue bounces C through LDS (stride 136 —
// measured 4.2M conflict-cycles vs 21M at 144) for full-16B global stores.
__global__ __launch_bounds__(256, 3) void xproj_gemm_kernel(
    const unsigned short* __restrict__ A,   // [Mc][1024]
    const unsigned short* __restrict__ Bt,  // [4096][1024]
    unsigned short* __restrict__ C,         // [Mc][4096]
    int Mc) {
  __shared__ __align__(16) char smem[34816];          // 34 KB union
  unsigned short* lsA = (unsigned short*)smem;        // [128*64]
  unsigned short* lsB = lsA + 8192;                   // [128*64]
  int xcd = blockIdx.x & 7;               // HW round-robin block->XCD
  int i5 = blockIdx.x >> 3;
  int bn = xcd * 4 + (i5 & 3);            // 4 B-panels per XCD (1MB, L2)
  int bm = i5 >> 2;
  int m0 = bm * 128, n0 = bn * 128;
  int tid = threadIdx.x, w = tid >> 6, lane = tid & 63;
  int wm = w >> 1, wn = w & 1;
  int l15 = lane & 15, l4 = lane >> 4;

  f32x4 acc[4][4];
#pragma unroll
  for (int i = 0; i < 4; ++i)
#pragma unroll
    for (int j = 0; j < 4; ++j) acc[i][j] = (f32x4)0.f;

  for (int ks = 0; ks < 16; ++ks) {
    int kk = ks * 64;
    __syncthreads();   // everyone done reading previous tile
#pragma unroll
    for (int ld = 0; ld < 4; ++ld) {
      int cid = ld * 256 + tid;
      int r = cid >> 3, kc = (cid & 7) * 8;
      int sk = kk + (kc ^ ((r & 7) << 3));
      gload16(&A[(size_t)(m0 + r) * 1024 + sk], &lsA[(ld * 256 + w * 64) * 8]);
      gload16(&Bt[(size_t)(n0 + r) * 1024 + sk], &lsB[(ld * 256 + w * 64) * 8]);
    }
    __syncthreads();   // data ready (drains vmcnt)
    bf16x8 af[4][2], bfr[4][2];
#pragma unroll
    for (int cm = 0; cm < 4; ++cm)
#pragma unroll
      for (int kss = 0; kss < 2; ++kss) {
        int e = (wm * 64 + cm * 16 + l15) * 64 + kss * 32 + l4 * 8;
        af[cm][kss] = *(const bf16x8*)&lsA[swz(e)];
      }
#pragma unroll
    for (int cn = 0; cn < 4; ++cn)
#pragma unroll
      for (int kss = 0; kss < 2; ++kss) {
        int e = (wn * 64 + cn * 16 + l15) * 64 + kss * 32 + l4 * 8;
        bfr[cn][kss] = *(const bf16x8*)&lsB[swz(e)];
      }
    __builtin_amdgcn_s_setprio(1);
#pragma unroll
    for (int cm = 0; cm < 4; ++cm)
#pragma unroll
      for (int cn = 0; cn < 4; ++cn)
#pragma unroll
        for (int kss = 0; kss < 2; ++kss)
          acc[cm][cn] = __builtin_amdgcn_mfma_f32_16x16x32_bf16(
              af[cm][kss], bfr[cn][kss], acc[cm][cn], 0, 0, 0);
    __builtin_amdgcn_s_setprio(0);
  }

  // ---- epilogue: acc -> LDS (bf16) -> coalesced 16B global stores ----
  __syncthreads();
  unsigned short* lsC = (unsigned short*)smem;   // [128][136]
#pragma unroll
  for (int cm = 0; cm < 4; ++cm)
#pragma unroll
    for (int cn = 0; cn < 4; ++cn)
#pragma unroll
      for (int r = 0; r < 4; ++r) {
        int row = wm * 64 + cm * 16 + l4 * 4 + r;
        int col = wn * 64 + cn * 16 + l15;
        lsC[row * 136 + col] = f2bf(acc[cm][cn][r]);
      }
  __syncthreads();
#pragma unroll
  for (int u = 0; u < 8; ++u) {
    int chunk = u * 256 + tid;        // 0..2047 : 128 rows x 16 chunks of 16B
    int row = chunk >> 4, c8 = chunk & 15;
    bf16x8 v = *(const bf16x8*)&lsC[row * 136 + c8 * 8];
    *(bf16x8*)&C[(size_t)(m0 + row) * 4096 + n0 + c8 * 8] = v;
  }
}

// ---------------- fused LSTM step (per-step launch) ----------------
// Tile (32 batch x 64 hidden x 4 gates), 256 threads / 4 waves, 72KB LDS
// -> grid 512 = 2 blocks/CU: each SIMD hosts 1 wave from each of 2
// INDEPENDENT barrier groups, so one block's vmcnt/barrier stalls overlap
// the other block's compute (decorrelation; was 1 block/CU fully exposed).
// A-rows reindexed [b_half][gate][b_lo] so every wave owns all 4 gates for
// its 16 b-rows -> epilogue stays wave-local. XCD map: XCD x owns
// bb in {4x..4x+3} (1MB Wh) + all bj (2MB hT) -> L2-resident staging.
// Single-barrier 3-buffer pipeline, counted vmcnt (6-load stages).
__global__ __launch_bounds__(256) void lstm_step_kernel(
    const unsigned short* __restrict__ Wh,   // [4096][1024]
    const unsigned short* __restrict__ hT,   // [1024][1024]  hT[j][k]=h[k][j]
    const unsigned short* __restrict__ Xp,   // [1024][4096]  this step's x-proj
    const float* __restrict__ bias,          // [4096]
    float* __restrict__ cst,                 // [1024*1024] fp32 cell state
    float* __restrict__ out_h,               // d_out + t*1M
    float* __restrict__ out_ht,              // d_out + T*1M
    float* __restrict__ out_ct,              // d_out + T*1M + 1M
    unsigned short* __restrict__ hT_next,    // other hT buffer
    int isLast) {
  __shared__ unsigned short lsA[3][128 * 64];  // [b_half][gate][b_lo] x 64k
  __shared__ unsigned short lsB[3][64 * 64];
  int bx = blockIdx.x;
  int xcd = bx & 7, idx = bx >> 3;             // idx in [0,64)
  int bb = xcd * 4 + (idx & 3);                // [0,32): XCD-local Wh slice
  int bj = idx >> 2;                           // [0,16)
  int b0 = bb * 32, j0 = bj * 64;
  int tid = threadIdx.x, w = tid >> 6, lane = tid & 63;
  int wm = w >> 1, wn = w & 1;
  int l15 = lane & 15, l4 = lane >> 4;
  int bbase = b0 + wm * 16 + l4 * 4;

  // ---- prefetch epilogue operands (issued first -> oldest in vmcnt FIFO;
  //      it0's vmcnt(6) drains them along with stage(0)) ----
  float bias_pre[4][2];
  float c_pre[2][4];
  unsigned short xp_pre[4][2][4];
#pragma unroll
  for (int n = 0; n < 2; ++n) {
    int j = j0 + wn * 32 + n * 16 + l15;
#pragma unroll
    for (int g = 0; g < 4; ++g) bias_pre[g][n] = bias[g * 1024 + j];
#pragma unroll
    for (int r = 0; r < 4; ++r) {
      c_pre[n][r] = cst[(size_t)(bbase + r) * 1024 + j];
#pragma unroll
      for (int g = 0; g < 4; ++g)
        xp_pre[g][n][r] = Xp[(size_t)(bbase + r) * 4096 + g * 1024 + j];
    }
  }

  f32x4 acc[4][2];
#pragma unroll
  for (int g = 0; g < 4; ++g)
#pragma unroll
    for (int n = 0; n < 2; ++n) acc[g][n] = (f32x4)0.f;

  auto stage = [&](int buf, int kk) {          // 6 gload16 per thread
#pragma unroll
    for (int ld = 0; ld < 4; ++ld) {
      int cid = ld * 256 + tid;
      int r = cid >> 3, kc = (cid & 7) * 8;    // r: 0..127 local A-row
      int sk = kk + (kc ^ ((r & 7) << 3));
      // local row r = b_half*64 + g*16 + b_lo  ->  Wh row g*1024 + b0 + b
      int grow = ((r >> 4) & 3) * 1024 + b0 + (r >> 6) * 16 + (r & 15);
      gload16(&Wh[(size_t)grow * 1024 + sk], &lsA[buf][(ld * 256 + w * 64) * 8]);
    }
#pragma unroll
    for (int u = 0; u < 2; ++u) {
      int cid = u * 256 + tid;
      int r = cid >> 3, kc = (cid & 7) * 8;    // r: 0..63
      int sk = kk + (kc ^ ((r & 7) << 3));
      gload16(&hT[(size_t)(j0 + r) * 1024 + sk], &lsB[buf][(u * 256 + w * 64) * 8]);
    }
  };
  auto compute = [&](int buf) {
    bf16x8 af[4][2], bfr[2][2];
#pragma unroll
    for (int g = 0; g < 4; ++g)
#pragma unroll
      for (int kss = 0; kss < 2; ++kss) {
        int e = (wm * 64 + g * 16 + l15) * 64 + kss * 32 + l4 * 8;
        af[g][kss] = *(const bf16x8*)&lsA[buf][swz(e)];
      }
#pragma unroll
    for (int n = 0; n < 2; ++n)
#pragma unroll
      for (int kss = 0; kss < 2; ++kss) {
        int e = (wn * 32 + n * 16 + l15) * 64 + kss * 32 + l4 * 8;
        bfr[n][kss] = *(const bf16x8*)&lsB[buf][swz(e)];
      }
    __builtin_amdgcn_s_setprio(1);
#pragma unroll
    for (int g = 0; g < 4; ++g)
#pragma unroll
      for (int n = 0; n < 2; ++n)
#pragma unroll
        for (int kss = 0; kss < 2; ++kss)
          acc[g][n] = __builtin_amdgcn_mfma_f32_16x16x32_bf16(
              af[g][kss], bfr[n][kss], acc[g][n], 0, 0, 0);
    __builtin_amdgcn_s_setprio(0);
  };

  // prologue: 2 stages in flight (48 prefetch + 12 staging = 60 <= 63)
  stage(0, 0);
  stage(1, 64);
#pragma unroll
  for (int it = 0; it < 16; ++it) {
    // my stage(it) landed (leaves stage(it+1)'s 6 loads in flight)
    if (it < 15) asm volatile("s_waitcnt vmcnt(6)" ::: "memory");
    else         asm volatile("s_waitcnt vmcnt(0)" ::: "memory");
    __builtin_amdgcn_sched_barrier(0);
    __builtin_amdgcn_s_barrier();     // stage(it) landed + prev reads retired
    __builtin_amdgcn_sched_barrier(0);
    if (it + 2 < 16) stage((it + 2) % 3, (it + 2) * 64);  // overwrite safe now
    compute(it % 3);
    asm volatile("s_waitcnt lgkmcnt(0)" ::: "memory");    // my ds_reads done
    __builtin_amdgcn_sched_barrier(0);
  }

  // epilogue: gates + cell/hidden update (operands already in registers)
#pragma unroll
  for (int n = 0; n < 2; ++n) {
    int j = j0 + wn * 32 + n * 16 + l15;
    float hn[4], cn[4];
#pragma unroll
    for (int r = 0; r < 4; ++r) {
      int b = bbase + r;
      float pi = acc[0][n][r] + bf2f(xp_pre[0][n][r]) + bias_pre[0][n];
      float pf = acc[1][n][r] + bf2f(xp_pre[1][n][r]) + bias_pre[1][n];
      float pg = acc[2][n][r] + bf2f(xp_pre[2][n][r]) + bias_pre[2][n];
      float po = acc[3][n][r] + bf2f(xp_pre[3][n][r]) + bias_pre[3][n];
      float ig = sigm(pi), fg = sigm(pf), gg = tanh_f(pg), og = sigm(po);
      float c_new = fg * c_pre[n][r] + ig * gg;
      cst[(size_t)b * 1024 + j] = c_new;
      cn[r] = c_new;
      hn[r] = og * tanh_f(c_new);
      out_h[(size_t)b * 1024 + j] = hn[r];
    }
    unsigned long long hp = (unsigned long long)f2bf(hn[0]) |
                            ((unsigned long long)f2bf(hn[1]) << 16) |
                            ((unsigned long long)f2bf(hn[2]) << 32) |
                            ((unsigned long long)f2bf(hn[3]) << 48);
    *(unsigned long long*)&hT_next[(size_t)j * 1024 + bbase] = hp;
    if (isLast) {
#pragma unroll
      for (int r = 0; r < 4; ++r) {
        int b = bbase + r;
        out_ht[(size_t)b * 1024 + j] = hn[r];
        out_ct[(size_t)b * 1024 + j] = cn[r];
      }
    }
  }
}

// ---------------- host ----------------
extern "C" void kernel_launch(void* const* d_in, const int* in_sizes, int n_in,
                              void* d_out, int out_size, void* d_ws, size_t ws_size,
                              hipStream_t stream) {
  const float* X   = (const float*)d_in[0];
  const float* Wii = (const float*)d_in[1];
  const float* Whi = (const float*)d_in[2];
  const float* bi  = (const float*)d_in[3];
  const float* Wif = (const float*)d_in[4];
  const float* Whf = (const float*)d_in[5];
  const float* bfv = (const float*)d_in[6];
  const float* Wig = (const float*)d_in[7];
  const float* Whg = (const float*)d_in[8];
  const float* bg  = (const float*)d_in[9];
  const float* Wio = (const float*)d_in[10];
  const float* Who = (const float*)d_in[11];
  const float* bo  = (const float*)d_in[12];
  float* out = (float*)d_out;

  char* wsp = (char*)d_ws;
  size_t off = 0;
  auto walloc = [&](size_t b) -> void* {
    void* p = wsp + off;
    off += (b + 255) & ~(size_t)255;
    return p;
  };
  unsigned short* WiT = (unsigned short*)walloc(4096ull * 1024 * 2);
  unsigned short* Wh  = (unsigned short*)walloc(4096ull * 1024 * 2);
  float* bias = (float*)walloc(4096 * 4);
  unsigned short* hT0 = (unsigned short*)walloc(1024ull * 1024 * 2);
  unsigned short* hT1 = (unsigned short*)walloc(1024ull * 1024 * 2);
  float* cbuf = (float*)walloc(1024ull * 1024 * 4);
  size_t fixed = off;

  long long avail = (long long)ws_size - (long long)fixed - (1ll << 20);
  int Tc = (int)(avail / (10ll << 20));   // 2MB Xbf + 8MB Xproj per step
  if (Tc < 1) Tc = 1;
  if (Tc > 128) Tc = 128;
  unsigned short* Xbf = (unsigned short*)walloc((size_t)Tc * 1024 * 1024 * 2);
  unsigned short* Xp  = (unsigned short*)walloc((size_t)Tc * 1024 * 4096 * 2);

  conv_wh_kernel<<<4096, 256, 0, stream>>>((const float4*)Whi, (const float4*)Whf,
                                           (const float4*)Whg, (const float4*)Who,
                                           (unsigned long long*)Wh);
  conv_wiT_kernel<<<1024, 256, 0, stream>>>(Wii, Wif, Wig, Wio, WiT);
  conv_bias_kernel<<<16, 256, 0, stream>>>(bi, bfv, bg, bo, bias);
  hipMemsetAsync(hT0, 0, 1024ull * 1024 * 2, stream);
  hipMemsetAsync(cbuf, 0, 1024ull * 1024 * 4, stream);

  for (int t0 = 0; t0 < 128; t0 += Tc) {
    int tc = (128 - t0 < Tc) ? (128 - t0) : Tc;
    int n4 = tc * 262144;
    conv_x_kernel<<<n4 / 256, 256, 0, stream>>>(
        (const float4*)(X + (size_t)t0 * 1048576),
        (unsigned long long*)Xbf, n4);
    xproj_gemm_kernel<<<tc * 256, 256, 0, stream>>>(Xbf, WiT, Xp, tc * 1024);
    for (int i = 0; i < tc; ++i) {
      int t = t0 + i;
      lstm_step_kernel<<<512, 256, 0, stream>>>(
          Wh, (t & 1) ? hT1 : hT0,
          Xp + (size_t)i * 1024 * 4096,
          bias, cbuf,
          out + (size_t)t * 1048576,
          out + 134217728ull,
          out + 135266304ull,
          (t & 1) ? hT0 : hT1,
          (t == 127) ? 1 : 0);
    }
  }
}